// Round 15
// baseline (114.277 us; speedup 1.0000x reference)
//
#include <hip/hip_runtime.h>
#include <hip/hip_bf16.h>
#include <math.h>

#define IN_DIM     128
#define OUT_DIM    64
#define BSHIFT     8                  // 256 nodes per bucket
#define BSZ        256
#define NBUCK_MAX  512                // covers N <= 131072
#define EPB        8192               // edges per block in bucket pass
#define CAPMAX     5120               // LDS staging limit (20 KB)

typedef __attribute__((ext_vector_type(4))) float  f32x4;
typedef __attribute__((ext_vector_type(8))) short  bf16x8;

// bf16 helpers
__device__ __forceinline__ unsigned int pk_bf2(float lo, float hi) {
    __hip_bfloat162 h = __float22bfloat162_rn(make_float2(lo, hi));
    unsigned int u;
    __builtin_memcpy(&u, &h, 4);
    return u;
}
__device__ __forceinline__ float bf_lo(unsigned int v) { return __uint_as_float(v << 16); }
__device__ __forceinline__ float bf_hi(unsigned int v) { return __uint_as_float(v & 0xFFFF0000u); }

// ---------------------------------------------------------------------------
// prep0: zero bcursor + pack W into MFMA B-frag order (bf16, 16 KB)
// ---------------------------------------------------------------------------
__global__ __launch_bounds__(256) void prep0_kernel(
        const float* __restrict__ W, unsigned int* __restrict__ wtab,
        int* __restrict__ bcursor) {
    const int tid = threadIdx.x;
    for (int i = tid; i < NBUCK_MAX; i += 256) bcursor[i] = 0;
#pragma unroll
    for (int ii = 0; ii < 4; ++ii) {
        int fl = ii * 256 + tid, f = fl >> 6, lane = fl & 63;
        int ct = f >> 2, kt = f & 3;
        int n  = ct * 16 + (lane & 15);
        int kb = kt * 32 + (lane >> 4) * 8;
        unsigned int q[4];
#pragma unroll
        for (int e = 0; e < 4; ++e)
            q[e] = pk_bf2(W[(kb + 2 * e) * OUT_DIM + n],
                          W[(kb + 2 * e + 1) * OUT_DIM + n]);
        *reinterpret_cast<uint4*>(&wtab[fl * 4]) = *reinterpret_cast<uint4*>(q);
    }
}

// ---------------------------------------------------------------------------
// fusedA (spatial partition, block-uniform branch):
//   blocks [0, nchunk):         bucket scatter of packed (r<<8 | c&255)
//   blocks [nchunk, +nblk_lin): MFMA linear, hsb = bf16(x @ W)   [UNscaled]
// The two halves are fully data-independent.
// ---------------------------------------------------------------------------
__global__ __launch_bounds__(256) void fusedA_kernel(
        const int* __restrict__ eidx, const float* __restrict__ x,
        const unsigned int* __restrict__ wtab,
        int* __restrict__ bcursor, int* __restrict__ tmp,
        unsigned int* __restrict__ hsb,
        int E, int N, int nbuck, int CAP, int nchunk) {
    __shared__ int hcnt[NBUCK_MAX];
    __shared__ int hbase[NBUCK_MAX];

    const int tid = threadIdx.x;

    if (blockIdx.x < nchunk) {
        // ---------------- bucket scatter ----------------
        for (int i = tid; i < nbuck; i += 256) hcnt[i] = 0;
        __syncthreads();

        const int base = blockIdx.x * EPB;
        const int end  = min(base + EPB, E);
        const int* col = eidx + E;

        for (int e = base + tid; e < end; e += 256)
            atomicAdd(&hcnt[col[e] >> BSHIFT], 1);
        __syncthreads();

        for (int i = tid; i < nbuck; i += 256) {
            int n = hcnt[i];
            hbase[i] = n ? (i * CAP + atomicAdd(&bcursor[i], n)) : 0;
            hcnt[i] = 0;                    // reuse as local cursor
        }
        __syncthreads();

        for (int e = base + tid; e < end; e += 256) {
            int r = eidx[e];
            int c = col[e];
            int bb = c >> BSHIFT;
            int ofs = atomicAdd(&hcnt[bb], 1);
            int pos = hbase[bb] + ofs;
            if (pos < (bb + 1) * CAP)       // overflow guard (8-sigma margin)
                tmp[pos] = (r << BSHIFT) | (c & (BSZ - 1));
        }
    } else {
        // ---------------- MFMA linear (unscaled) ----------------
        const int lane6 = tid & 63;
        const int wv    = tid >> 6;
        const int tile    = (blockIdx.x - nchunk) * 4 + wv;
        const int rowbase = tile * 16;
        if (rowbase >= N) return;

        bf16x8 b[16];
#pragma unroll
        for (int f = 0; f < 16; ++f)
            b[f] = *reinterpret_cast<const bf16x8*>(&wtab[(f * 64 + lane6) * 4]);

        const int arow  = rowbase + (lane6 & 15);
        const int kbase = (lane6 >> 4) * 8;
        bf16x8 a[4];
#pragma unroll
        for (int kt = 0; kt < 4; ++kt) {
            const float4* p = reinterpret_cast<const float4*>(
                &x[(size_t)arow * IN_DIM + kt * 32 + kbase]);
            float4 f0 = p[0], f1 = p[1];
            unsigned int q[4] = { pk_bf2(f0.x, f0.y), pk_bf2(f0.z, f0.w),
                                  pk_bf2(f1.x, f1.y), pk_bf2(f1.z, f1.w) };
            a[kt] = *reinterpret_cast<bf16x8*>(q);
        }

        f32x4 acc[4] = {{0,0,0,0},{0,0,0,0},{0,0,0,0},{0,0,0,0}};
#pragma unroll
        for (int ct = 0; ct < 4; ++ct)
#pragma unroll
            for (int kt = 0; kt < 4; ++kt)
                acc[ct] = __builtin_amdgcn_mfma_f32_16x16x32_bf16(
                    a[kt], b[ct * 4 + kt], acc[ct], 0, 0, 0);

        const int rbase = rowbase + (lane6 >> 4) * 4;
#pragma unroll
        for (int ct = 0; ct < 4; ++ct) {
#pragma unroll
            for (int r = 0; r < 4; ++r) {
                float v  = acc[ct][r];
                float vn = __shfl_down(v, 1, 64);
                if ((lane6 & 1) == 0) {
                    int cpair = ct * 8 + ((lane6 & 15) >> 1);
                    hsb[(size_t)(rbase + r) * (OUT_DIM / 2) + cpair] = pk_bf2(v, vn);
                }
            }
        }
    }
}

// ---------------------------------------------------------------------------
// sortloc: per-bucket LDS staging -> degree count -> rowptr + dis + bend,
// then exact CSR in place over the same tmp region.
// ---------------------------------------------------------------------------
__global__ __launch_bounds__(256) void sortloc_kernel(
        int* __restrict__ tmp, const int* __restrict__ bcursor,
        int* __restrict__ rowptr, float* __restrict__ dis,
        int* __restrict__ bend, int N, int CAP) {
    __shared__ int sedge[CAPMAX];          // 20 KB
    __shared__ int scnt[BSZ];
    __shared__ int spref[BSZ];
    __shared__ int sscur[BSZ];

    const int b    = blockIdx.x;
    const int tid  = threadIdx.x;
    const int base = b * CAP;
    const int cnt  = min(bcursor[b], CAP);

    scnt[tid] = 0;
    sscur[tid] = 0;
    __syncthreads();

    // load to LDS + count
    for (int i = tid; i < cnt; i += 256) {
        int p = tmp[base + i];
        sedge[i] = p;
        atomicAdd(&scnt[p & (BSZ - 1)], 1);
    }
    __syncthreads();

    // Hillis-Steele inclusive scan -> exclusive
    int v = scnt[tid];
    spref[tid] = v;
    __syncthreads();
    for (int off = 1; off < 256; off <<= 1) {
        int t2 = (tid >= off) ? spref[tid - off] : 0;
        __syncthreads();
        spref[tid] += t2;
        __syncthreads();
    }
    int excl = spref[tid] - v;

    const int node = (b << BSHIFT) + tid;
    if (node < N) {
        rowptr[node] = base + excl;
        dis[node] = (v > 0) ? rsqrtf((float)v) : 0.f;
    }
    spref[tid] = excl;
    if (tid == 0) bend[b] = base + cnt;
    __syncthreads();

    // exact CSR placement, in place (sources from LDS copy)
    for (int i = tid; i < cnt; i += 256) {
        int p = sedge[i];
        int c = p & (BSZ - 1);
        int pos = base + spref[c] + atomicAdd(&sscur[c], 1);
        tmp[pos] = p >> BSHIFT;
    }
}

// ---------------------------------------------------------------------------
// Aggregate + bias + PReLU: one wave per target node; each 32-lane half
// processes its own edge; per-edge dis[src] fold (L2-resident broadcast
// load); halves combined via shfl_xor(32). 8 gathers in flight per half.
// ---------------------------------------------------------------------------
__global__ __launch_bounds__(256) void agg_kernel(
        const int* __restrict__ rowptr, const int* __restrict__ src,
        const int* __restrict__ bend,
        const unsigned int* __restrict__ hsb, const float* __restrict__ dis,
        const float* __restrict__ b, const float* __restrict__ prelu_a,
        float* __restrict__ out, int N) {
    const int lane = threadIdx.x & 63;
    const int half = lane >> 5;
    const int l32  = lane & 31;
    const int node = (blockIdx.x * blockDim.x + threadIdx.x) >> 6;
    if (node >= N) return;

    const int beg = rowptr[node];
    const int nb1 = node + 1;
    const int end = ((nb1 & (BSZ - 1)) != 0 && nb1 < N) ? rowptr[nb1]
                                                        : bend[node >> BSHIFT];

    float a0 = 0.f, a1 = 0.f;
    int p = beg + half;
    for (; p + 14 < end; p += 16) {
        int r0 = src[p],      r1 = src[p + 2],  r2 = src[p + 4],  r3 = src[p + 6];
        int r4 = src[p + 8],  r5 = src[p + 10], r6 = src[p + 12], r7 = src[p + 14];
        float s0 = dis[r0], s1 = dis[r1], s2 = dis[r2], s3 = dis[r3];
        float s4 = dis[r4], s5 = dis[r5], s6 = dis[r6], s7 = dis[r7];
        unsigned int v0 = hsb[(size_t)r0 * (OUT_DIM / 2) + l32];
        unsigned int v1 = hsb[(size_t)r1 * (OUT_DIM / 2) + l32];
        unsigned int v2 = hsb[(size_t)r2 * (OUT_DIM / 2) + l32];
        unsigned int v3 = hsb[(size_t)r3 * (OUT_DIM / 2) + l32];
        unsigned int v4 = hsb[(size_t)r4 * (OUT_DIM / 2) + l32];
        unsigned int v5 = hsb[(size_t)r5 * (OUT_DIM / 2) + l32];
        unsigned int v6 = hsb[(size_t)r6 * (OUT_DIM / 2) + l32];
        unsigned int v7 = hsb[(size_t)r7 * (OUT_DIM / 2) + l32];
        a0 = fmaf(bf_lo(v0), s0, a0); a1 = fmaf(bf_hi(v0), s0, a1);
        a0 = fmaf(bf_lo(v1), s1, a0); a1 = fmaf(bf_hi(v1), s1, a1);
        a0 = fmaf(bf_lo(v2), s2, a0); a1 = fmaf(bf_hi(v2), s2, a1);
        a0 = fmaf(bf_lo(v3), s3, a0); a1 = fmaf(bf_hi(v3), s3, a1);
        a0 = fmaf(bf_lo(v4), s4, a0); a1 = fmaf(bf_hi(v4), s4, a1);
        a0 = fmaf(bf_lo(v5), s5, a0); a1 = fmaf(bf_hi(v5), s5, a1);
        a0 = fmaf(bf_lo(v6), s6, a0); a1 = fmaf(bf_hi(v6), s6, a1);
        a0 = fmaf(bf_lo(v7), s7, a0); a1 = fmaf(bf_hi(v7), s7, a1);
    }
    for (; p + 6 < end; p += 8) {
        int r0 = src[p], r1 = src[p + 2], r2 = src[p + 4], r3 = src[p + 6];
        float s0 = dis[r0], s1 = dis[r1], s2 = dis[r2], s3 = dis[r3];
        unsigned int v0 = hsb[(size_t)r0 * (OUT_DIM / 2) + l32];
        unsigned int v1 = hsb[(size_t)r1 * (OUT_DIM / 2) + l32];
        unsigned int v2 = hsb[(size_t)r2 * (OUT_DIM / 2) + l32];
        unsigned int v3 = hsb[(size_t)r3 * (OUT_DIM / 2) + l32];
        a0 = fmaf(bf_lo(v0), s0, a0); a1 = fmaf(bf_hi(v0), s0, a1);
        a0 = fmaf(bf_lo(v1), s1, a0); a1 = fmaf(bf_hi(v1), s1, a1);
        a0 = fmaf(bf_lo(v2), s2, a0); a1 = fmaf(bf_hi(v2), s2, a1);
        a0 = fmaf(bf_lo(v3), s3, a0); a1 = fmaf(bf_hi(v3), s3, a1);
    }
    for (; p < end; p += 2) {
        int r = src[p];
        float s = dis[r];
        unsigned int v = hsb[(size_t)r * (OUT_DIM / 2) + l32];
        a0 = fmaf(bf_lo(v), s, a0);
        a1 = fmaf(bf_hi(v), s, a1);
    }

    a0 += __shfl_xor(a0, 32, 64);
    a1 += __shfl_xor(a1, 32, 64);

    if (half == 0) {
        const float dn = dis[node];
        const float pa = prelu_a[0];
        int c0 = l32 * 2;
        float o0 = a0 * dn + b[c0];
        float o1 = a1 * dn + b[c0 + 1];
        o0 = (o0 >= 0.f) ? o0 : pa * o0;
        o1 = (o1 >= 0.f) ? o1 : pa * o1;
        *reinterpret_cast<float2*>(&out[(size_t)node * OUT_DIM + c0]) = make_float2(o0, o1);
    }
}

extern "C" void kernel_launch(void* const* d_in, const int* in_sizes, int n_in,
                              void* d_out, int out_size, void* d_ws, size_t ws_size,
                              hipStream_t stream) {
    const float* x    = (const float*)d_in[0];
    const int*   eidx = (const int*)d_in[1];
    const float* W    = (const float*)d_in[2];
    const float* b    = (const float*)d_in[3];
    const float* pa   = (const float*)d_in[4];
    float* out = (float*)d_out;

    const int N = in_sizes[0] / IN_DIM;        // 100000
    const int E = in_sizes[1] / 2;             // 1600000
    const int nbuck  = (N + BSZ - 1) >> BSHIFT;   // 391
    const int nchunk = (E + EPB - 1) / EPB;       // 196
    const int ntiles = (N + 15) / 16;             // 6250
    const int nblk_lin = (ntiles + 3) / 4;        // 1563

    // fixed bucket capacity: mean + 8 sigma, rounded to 256, capped by LDS
    int avg = E / nbuck;
    int CAP = ((avg + 8 * (int)sqrt((double)avg) + 255) / 256) * 256;
    if (CAP > CAPMAX) CAP = CAPMAX;

    // workspace layout (4-byte elements):
    unsigned int* hsb = (unsigned int*)d_ws;                  // N*32 (bf16x2)
    int*   bcursor = (int*)(hsb + (size_t)N * (OUT_DIM / 2)); // NBUCK_MAX
    int*   bend    = bcursor + NBUCK_MAX;                     // NBUCK_MAX
    int*   rowptr  = bend + NBUCK_MAX;                        // N
    float* dis     = (float*)(rowptr + N);                    // N
    int*   tmp     = (int*)(dis + N);                         // nbuck*CAP
    unsigned int* wtab = (unsigned int*)(tmp + (size_t)nbuck * CAP); // 4096

    // 1) zero bcursor + pack W frag table
    prep0_kernel<<<1, 256, 0, stream>>>(W, wtab, bcursor);

    // 2) fused: bucket scatter || MFMA linear (unscaled hsb)
    fusedA_kernel<<<nchunk + nblk_lin, 256, 0, stream>>>(
        eidx, x, wtab, bcursor, tmp, hsb, E, N, nbuck, CAP, nchunk);

    // 3) per-bucket count + in-place CSR placement; emits rowptr + dis + bend
    sortloc_kernel<<<nbuck, 256, 0, stream>>>(
        tmp, bcursor, rowptr, dis, bend, N, CAP);

    // 4) aggregate (per-edge dis[src] fold) + bias + PReLU
    agg_kernel<<<(N * 64 + 255) / 256, 256, 0, stream>>>(
        rowptr, tmp, bend, hsb, dis, b, pa, out, N);
}

// Round 16
// 105.096 us; speedup vs baseline: 1.0874x; 1.0874x over previous
//
#include <hip/hip_runtime.h>
#include <hip/hip_bf16.h>
#include <math.h>

#define IN_DIM     128
#define OUT_DIM    64
#define BSHIFT     8                  // 256 nodes per bucket
#define BSZ        256
#define NBUCK_MAX  512                // covers N <= 131072
#define EPB        4096               // edges per block in bucket pass
#define EPT        16                 // edges per thread (EPB/256)
#define CAPMAX     5120               // LDS staging limit (20 KB)

typedef __attribute__((ext_vector_type(4))) float  f32x4;
typedef __attribute__((ext_vector_type(8))) short  bf16x8;

// bf16 helpers
__device__ __forceinline__ unsigned int pk_bf2(float lo, float hi) {
    __hip_bfloat162 h = __float22bfloat162_rn(make_float2(lo, hi));
    unsigned int u;
    __builtin_memcpy(&u, &h, 4);
    return u;
}
__device__ __forceinline__ float bf_lo(unsigned int v) { return __uint_as_float(v << 16); }
__device__ __forceinline__ float bf_hi(unsigned int v) { return __uint_as_float(v & 0xFFFF0000u); }

// ---------------------------------------------------------------------------
// prep0: zero bcursor + pack W into MFMA B-frag order (bf16, 16 KB)
// ---------------------------------------------------------------------------
__global__ __launch_bounds__(256) void prep0_kernel(
        const float* __restrict__ W, unsigned int* __restrict__ wtab,
        int* __restrict__ bcursor) {
    const int tid = threadIdx.x;
    for (int i = tid; i < NBUCK_MAX; i += 256) bcursor[i] = 0;
#pragma unroll
    for (int ii = 0; ii < 4; ++ii) {
        int fl = ii * 256 + tid, f = fl >> 6, lane = fl & 63;
        int ct = f >> 2, kt = f & 3;
        int n  = ct * 16 + (lane & 15);
        int kb = kt * 32 + (lane >> 4) * 8;
        unsigned int q[4];
#pragma unroll
        for (int e = 0; e < 4; ++e)
            q[e] = pk_bf2(W[(kb + 2 * e) * OUT_DIM + n],
                          W[(kb + 2 * e + 1) * OUT_DIM + n]);
        *reinterpret_cast<uint4*>(&wtab[fl * 4]) = *reinterpret_cast<uint4*>(q);
    }
}

// ---------------------------------------------------------------------------
// Bucket scatter, SINGLE global pass: stage 16 edges/thread in registers
// (fully unrolled -> static indexing), LDS count, block-aggregated reserve,
// scatter from registers. tmp gets packed (r<<8 | c&255) at b*CAP regions.
// ---------------------------------------------------------------------------
__global__ __launch_bounds__(256) void bucket_kernel(
        const int* __restrict__ eidx, int* __restrict__ bcursor,
        int* __restrict__ tmp, int E, int nbuck, int CAP) {
    __shared__ int hcnt[NBUCK_MAX];
    __shared__ int hbase[NBUCK_MAX];
    const int tid = threadIdx.x;
    for (int i = tid; i < nbuck; i += 256) hcnt[i] = 0;
    __syncthreads();

    const int base = blockIdx.x * EPB;
    const int* col = eidx + E;

    int er[EPT], ec[EPT];
#pragma unroll
    for (int j = 0; j < EPT; ++j) {
        int e = base + j * 256 + tid;
        if (e < E) {
            er[j] = eidx[e];
            ec[j] = col[e];
            atomicAdd(&hcnt[ec[j] >> BSHIFT], 1);
        } else {
            ec[j] = -1;
        }
    }
    __syncthreads();

    for (int i = tid; i < nbuck; i += 256) {
        int n = hcnt[i];
        hbase[i] = n ? (i * CAP + atomicAdd(&bcursor[i], n)) : 0;
        hcnt[i] = 0;                        // reuse as local cursor
    }
    __syncthreads();

#pragma unroll
    for (int j = 0; j < EPT; ++j) {
        if (ec[j] >= 0) {
            int bb = ec[j] >> BSHIFT;
            int ofs = atomicAdd(&hcnt[bb], 1);
            int pos = hbase[bb] + ofs;
            if (pos < (bb + 1) * CAP)       // overflow guard (8-sigma margin)
                tmp[pos] = (er[j] << BSHIFT) | (ec[j] & (BSZ - 1));
        }
    }
}

// ---------------------------------------------------------------------------
// fusedB (spatial partition, block-uniform branch):
//   blocks [0, nbuck):          sortloc = count + scan + in-place CSR
//                               placement; emits rowptr + dis + bend
//   blocks [nbuck, +nblk_lin):  MFMA linear, hsb = bf16(x @ W)  [UNscaled]
// LDS-bound half paired with MFMA/stream half (complementary resources).
// ---------------------------------------------------------------------------
__global__ __launch_bounds__(256) void fusedB_kernel(
        int* __restrict__ tmp, const int* __restrict__ bcursor,
        int* __restrict__ rowptr, float* __restrict__ dis,
        int* __restrict__ bend,
        const float* __restrict__ x, const unsigned int* __restrict__ wtab,
        unsigned int* __restrict__ hsb, int N, int CAP, int nbuck) {
    __shared__ int sedge[CAPMAX];          // 20 KB
    __shared__ int scnt[BSZ];
    __shared__ int spref[BSZ];
    __shared__ int sscur[BSZ];

    const int tid = threadIdx.x;

    if (blockIdx.x < nbuck) {
        // ---------------- sortloc ----------------
        const int b    = blockIdx.x;
        const int base = b * CAP;
        const int cnt  = min(bcursor[b], CAP);

        scnt[tid] = 0;
        sscur[tid] = 0;
        __syncthreads();

        for (int i = tid; i < cnt; i += 256) {
            int p = tmp[base + i];
            sedge[i] = p;
            atomicAdd(&scnt[p & (BSZ - 1)], 1);
        }
        __syncthreads();

        int v = scnt[tid];
        spref[tid] = v;
        __syncthreads();
        for (int off = 1; off < 256; off <<= 1) {
            int t2 = (tid >= off) ? spref[tid - off] : 0;
            __syncthreads();
            spref[tid] += t2;
            __syncthreads();
        }
        int excl = spref[tid] - v;

        const int node = (b << BSHIFT) + tid;
        if (node < N) {
            rowptr[node] = base + excl;
            dis[node] = (v > 0) ? rsqrtf((float)v) : 0.f;
        }
        spref[tid] = excl;
        if (tid == 0) bend[b] = base + cnt;
        __syncthreads();

        for (int i = tid; i < cnt; i += 256) {
            int p = sedge[i];
            int c = p & (BSZ - 1);
            int pos = base + spref[c] + atomicAdd(&sscur[c], 1);
            tmp[pos] = p >> BSHIFT;
        }
    } else {
        // ---------------- MFMA linear (unscaled) ----------------
        const int lane6 = tid & 63;
        const int wv    = tid >> 6;
        const int tile    = (blockIdx.x - nbuck) * 4 + wv;
        const int rowbase = tile * 16;
        if (rowbase >= N) return;

        bf16x8 b[16];
#pragma unroll
        for (int f = 0; f < 16; ++f)
            b[f] = *reinterpret_cast<const bf16x8*>(&wtab[(f * 64 + lane6) * 4]);

        const int arow  = rowbase + (lane6 & 15);
        const int kbase = (lane6 >> 4) * 8;
        bf16x8 a[4];
#pragma unroll
        for (int kt = 0; kt < 4; ++kt) {
            const float4* p = reinterpret_cast<const float4*>(
                &x[(size_t)arow * IN_DIM + kt * 32 + kbase]);
            float4 f0 = p[0], f1 = p[1];
            unsigned int q[4] = { pk_bf2(f0.x, f0.y), pk_bf2(f0.z, f0.w),
                                  pk_bf2(f1.x, f1.y), pk_bf2(f1.z, f1.w) };
            a[kt] = *reinterpret_cast<bf16x8*>(q);
        }

        f32x4 acc[4] = {{0,0,0,0},{0,0,0,0},{0,0,0,0},{0,0,0,0}};
#pragma unroll
        for (int ct = 0; ct < 4; ++ct)
#pragma unroll
            for (int kt = 0; kt < 4; ++kt)
                acc[ct] = __builtin_amdgcn_mfma_f32_16x16x32_bf16(
                    a[kt], b[ct * 4 + kt], acc[ct], 0, 0, 0);

        const int rbase = rowbase + (lane6 >> 4) * 4;
#pragma unroll
        for (int ct = 0; ct < 4; ++ct) {
#pragma unroll
            for (int r = 0; r < 4; ++r) {
                float v  = acc[ct][r];
                float vn = __shfl_down(v, 1, 64);
                if ((lane6 & 1) == 0) {
                    int cpair = ct * 8 + ((lane6 & 15) >> 1);
                    hsb[(size_t)(rbase + r) * (OUT_DIM / 2) + cpair] = pk_bf2(v, vn);
                }
            }
        }
    }
}

// ---------------------------------------------------------------------------
// Aggregate + bias + PReLU: one wave per target node; each 32-lane half
// processes its own edge; per-edge dis[src] fold (L2-resident broadcast
// load); halves combined via shfl_xor(32). 8 gathers in flight per half.
// ---------------------------------------------------------------------------
__global__ __launch_bounds__(256) void agg_kernel(
        const int* __restrict__ rowptr, const int* __restrict__ src,
        const int* __restrict__ bend,
        const unsigned int* __restrict__ hsb, const float* __restrict__ dis,
        const float* __restrict__ b, const float* __restrict__ prelu_a,
        float* __restrict__ out, int N) {
    const int lane = threadIdx.x & 63;
    const int half = lane >> 5;
    const int l32  = lane & 31;
    const int node = (blockIdx.x * blockDim.x + threadIdx.x) >> 6;
    if (node >= N) return;

    const int beg = rowptr[node];
    const int nb1 = node + 1;
    const int end = ((nb1 & (BSZ - 1)) != 0 && nb1 < N) ? rowptr[nb1]
                                                        : bend[node >> BSHIFT];

    float a0 = 0.f, a1 = 0.f;
    int p = beg + half;
    for (; p + 14 < end; p += 16) {
        int r0 = src[p],      r1 = src[p + 2],  r2 = src[p + 4],  r3 = src[p + 6];
        int r4 = src[p + 8],  r5 = src[p + 10], r6 = src[p + 12], r7 = src[p + 14];
        float s0 = dis[r0], s1 = dis[r1], s2 = dis[r2], s3 = dis[r3];
        float s4 = dis[r4], s5 = dis[r5], s6 = dis[r6], s7 = dis[r7];
        unsigned int v0 = hsb[(size_t)r0 * (OUT_DIM / 2) + l32];
        unsigned int v1 = hsb[(size_t)r1 * (OUT_DIM / 2) + l32];
        unsigned int v2 = hsb[(size_t)r2 * (OUT_DIM / 2) + l32];
        unsigned int v3 = hsb[(size_t)r3 * (OUT_DIM / 2) + l32];
        unsigned int v4 = hsb[(size_t)r4 * (OUT_DIM / 2) + l32];
        unsigned int v5 = hsb[(size_t)r5 * (OUT_DIM / 2) + l32];
        unsigned int v6 = hsb[(size_t)r6 * (OUT_DIM / 2) + l32];
        unsigned int v7 = hsb[(size_t)r7 * (OUT_DIM / 2) + l32];
        a0 = fmaf(bf_lo(v0), s0, a0); a1 = fmaf(bf_hi(v0), s0, a1);
        a0 = fmaf(bf_lo(v1), s1, a0); a1 = fmaf(bf_hi(v1), s1, a1);
        a0 = fmaf(bf_lo(v2), s2, a0); a1 = fmaf(bf_hi(v2), s2, a1);
        a0 = fmaf(bf_lo(v3), s3, a0); a1 = fmaf(bf_hi(v3), s3, a1);
        a0 = fmaf(bf_lo(v4), s4, a0); a1 = fmaf(bf_hi(v4), s4, a1);
        a0 = fmaf(bf_lo(v5), s5, a0); a1 = fmaf(bf_hi(v5), s5, a1);
        a0 = fmaf(bf_lo(v6), s6, a0); a1 = fmaf(bf_hi(v6), s6, a1);
        a0 = fmaf(bf_lo(v7), s7, a0); a1 = fmaf(bf_hi(v7), s7, a1);
    }
    for (; p + 6 < end; p += 8) {
        int r0 = src[p], r1 = src[p + 2], r2 = src[p + 4], r3 = src[p + 6];
        float s0 = dis[r0], s1 = dis[r1], s2 = dis[r2], s3 = dis[r3];
        unsigned int v0 = hsb[(size_t)r0 * (OUT_DIM / 2) + l32];
        unsigned int v1 = hsb[(size_t)r1 * (OUT_DIM / 2) + l32];
        unsigned int v2 = hsb[(size_t)r2 * (OUT_DIM / 2) + l32];
        unsigned int v3 = hsb[(size_t)r3 * (OUT_DIM / 2) + l32];
        a0 = fmaf(bf_lo(v0), s0, a0); a1 = fmaf(bf_hi(v0), s0, a1);
        a0 = fmaf(bf_lo(v1), s1, a0); a1 = fmaf(bf_hi(v1), s1, a1);
        a0 = fmaf(bf_lo(v2), s2, a0); a1 = fmaf(bf_hi(v2), s2, a1);
        a0 = fmaf(bf_lo(v3), s3, a0); a1 = fmaf(bf_hi(v3), s3, a1);
    }
    for (; p < end; p += 2) {
        int r = src[p];
        float s = dis[r];
        unsigned int v = hsb[(size_t)r * (OUT_DIM / 2) + l32];
        a0 = fmaf(bf_lo(v), s, a0);
        a1 = fmaf(bf_hi(v), s, a1);
    }

    a0 += __shfl_xor(a0, 32, 64);
    a1 += __shfl_xor(a1, 32, 64);

    if (half == 0) {
        const float dn = dis[node];
        const float pa = prelu_a[0];
        int c0 = l32 * 2;
        float o0 = a0 * dn + b[c0];
        float o1 = a1 * dn + b[c0 + 1];
        o0 = (o0 >= 0.f) ? o0 : pa * o0;
        o1 = (o1 >= 0.f) ? o1 : pa * o1;
        *reinterpret_cast<float2*>(&out[(size_t)node * OUT_DIM + c0]) = make_float2(o0, o1);
    }
}

extern "C" void kernel_launch(void* const* d_in, const int* in_sizes, int n_in,
                              void* d_out, int out_size, void* d_ws, size_t ws_size,
                              hipStream_t stream) {
    const float* x    = (const float*)d_in[0];
    const int*   eidx = (const int*)d_in[1];
    const float* W    = (const float*)d_in[2];
    const float* b    = (const float*)d_in[3];
    const float* pa   = (const float*)d_in[4];
    float* out = (float*)d_out;

    const int N = in_sizes[0] / IN_DIM;        // 100000
    const int E = in_sizes[1] / 2;             // 1600000
    const int nbuck  = (N + BSZ - 1) >> BSHIFT;   // 391
    const int nchunk = (E + EPB - 1) / EPB;       // 391
    const int ntiles = (N + 15) / 16;             // 6250
    const int nblk_lin = (ntiles + 3) / 4;        // 1563

    // fixed bucket capacity: mean + 8 sigma, rounded to 256, capped by LDS
    int avg = E / nbuck;
    int CAP = ((avg + 8 * (int)sqrt((double)avg) + 255) / 256) * 256;
    if (CAP > CAPMAX) CAP = CAPMAX;

    // workspace layout (4-byte elements):
    unsigned int* hsb = (unsigned int*)d_ws;                  // N*32 (bf16x2)
    int*   bcursor = (int*)(hsb + (size_t)N * (OUT_DIM / 2)); // NBUCK_MAX
    int*   bend    = bcursor + NBUCK_MAX;                     // NBUCK_MAX
    int*   rowptr  = bend + NBUCK_MAX;                        // N
    float* dis     = (float*)(rowptr + N);                    // N
    int*   tmp     = (int*)(dis + N);                         // nbuck*CAP
    unsigned int* wtab = (unsigned int*)(tmp + (size_t)nbuck * CAP); // 4096

    // 1) zero bcursor + pack W frag table
    prep0_kernel<<<1, 256, 0, stream>>>(W, wtab, bcursor);

    // 2) bucket scatter (single global pass, register-staged)
    bucket_kernel<<<nchunk, 256, 0, stream>>>(eidx, bcursor, tmp, E, nbuck, CAP);

    // 3) fused: sortloc (count+scan+place, emits rowptr/dis/bend) || MFMA linear
    fusedB_kernel<<<nbuck + nblk_lin, 256, 0, stream>>>(
        tmp, bcursor, rowptr, dis, bend, x, wtab, hsb, N, CAP, nbuck);

    // 4) aggregate (per-edge dis[src] fold) + bias + PReLU
    agg_kernel<<<(N * 64 + 255) / 256, 256, 0, stream>>>(
        rowptr, tmp, bend, hsb, dis, b, pa, out, N);
}

// Round 17
// 100.848 us; speedup vs baseline: 1.1332x; 1.0421x over previous
//
#include <hip/hip_runtime.h>
#include <hip/hip_bf16.h>
#include <math.h>

#define IN_DIM     128
#define OUT_DIM    64
#define BSHIFT     8                  // 256 nodes per bucket
#define BSZ        256
#define NBUCK_MAX  512                // covers N <= 131072
#define EPB        4096               // edges per block in bucket pass
#define EPT        16                 // edges per thread (EPB/256)
#define CAPMAX     5120               // LDS staging limit (20 KB)

typedef __attribute__((ext_vector_type(4))) float  f32x4;
typedef __attribute__((ext_vector_type(8))) short  bf16x8;

// bf16 helpers
__device__ __forceinline__ unsigned int pk_bf2(float lo, float hi) {
    __hip_bfloat162 h = __float22bfloat162_rn(make_float2(lo, hi));
    unsigned int u;
    __builtin_memcpy(&u, &h, 4);
    return u;
}
__device__ __forceinline__ float bf_lo(unsigned int v) { return __uint_as_float(v << 16); }
__device__ __forceinline__ float bf_hi(unsigned int v) { return __uint_as_float(v & 0xFFFF0000u); }

// ---------------------------------------------------------------------------
// prep0: zero bcursor + pack W into MFMA B-frag order (bf16, 16 KB)
// ---------------------------------------------------------------------------
__global__ __launch_bounds__(256) void prep0_kernel(
        const float* __restrict__ W, unsigned int* __restrict__ wtab,
        int* __restrict__ bcursor) {
    const int tid = threadIdx.x;
    for (int i = tid; i < NBUCK_MAX; i += 256) bcursor[i] = 0;
#pragma unroll
    for (int ii = 0; ii < 4; ++ii) {
        int fl = ii * 256 + tid, f = fl >> 6, lane = fl & 63;
        int ct = f >> 2, kt = f & 3;
        int n  = ct * 16 + (lane & 15);
        int kb = kt * 32 + (lane >> 4) * 8;
        unsigned int q[4];
#pragma unroll
        for (int e = 0; e < 4; ++e)
            q[e] = pk_bf2(W[(kb + 2 * e) * OUT_DIM + n],
                          W[(kb + 2 * e + 1) * OUT_DIM + n]);
        *reinterpret_cast<uint4*>(&wtab[fl * 4]) = *reinterpret_cast<uint4*>(q);
    }
}

// ---------------------------------------------------------------------------
// Bucket scatter, SINGLE global pass: stage 16 edges/thread in registers
// (fully unrolled -> static indexing), LDS count, block-aggregated reserve,
// scatter from registers. tmp gets packed (r<<8 | c&255) at b*CAP regions.
// ---------------------------------------------------------------------------
__global__ __launch_bounds__(256) void bucket_kernel(
        const int* __restrict__ eidx, int* __restrict__ bcursor,
        int* __restrict__ tmp, int E, int nbuck, int CAP) {
    __shared__ int hcnt[NBUCK_MAX];
    __shared__ int hbase[NBUCK_MAX];
    const int tid = threadIdx.x;
    for (int i = tid; i < nbuck; i += 256) hcnt[i] = 0;
    __syncthreads();

    const int base = blockIdx.x * EPB;
    const int* col = eidx + E;

    int er[EPT], ec[EPT];
#pragma unroll
    for (int j = 0; j < EPT; ++j) {
        int e = base + j * 256 + tid;
        if (e < E) {
            er[j] = eidx[e];
            ec[j] = col[e];
            atomicAdd(&hcnt[ec[j] >> BSHIFT], 1);
        } else {
            ec[j] = -1;
        }
    }
    __syncthreads();

    for (int i = tid; i < nbuck; i += 256) {
        int n = hcnt[i];
        hbase[i] = n ? (i * CAP + atomicAdd(&bcursor[i], n)) : 0;
        hcnt[i] = 0;                        // reuse as local cursor
    }
    __syncthreads();

#pragma unroll
    for (int j = 0; j < EPT; ++j) {
        if (ec[j] >= 0) {
            int bb = ec[j] >> BSHIFT;
            int ofs = atomicAdd(&hcnt[bb], 1);
            int pos = hbase[bb] + ofs;
            if (pos < (bb + 1) * CAP)       // overflow guard (8-sigma margin)
                tmp[pos] = (er[j] << BSHIFT) | (ec[j] & (BSZ - 1));
        }
    }
}

// ---------------------------------------------------------------------------
// fusedB (spatial partition, block-uniform branch):
//   blocks [0, nbuck):          sortloc = count + scan + in-place CSR
//                               placement; emits rowptr + dis + bend
//   blocks [nbuck, +nblk_lin):  MFMA linear, hsb = bf16(x @ W)  [UNscaled]
// ---------------------------------------------------------------------------
__global__ __launch_bounds__(256) void fusedB_kernel(
        int* __restrict__ tmp, const int* __restrict__ bcursor,
        int* __restrict__ rowptr, float* __restrict__ dis,
        int* __restrict__ bend,
        const float* __restrict__ x, const unsigned int* __restrict__ wtab,
        unsigned int* __restrict__ hsb, int N, int CAP, int nbuck) {
    __shared__ int sedge[CAPMAX];          // 20 KB
    __shared__ int scnt[BSZ];
    __shared__ int spref[BSZ];
    __shared__ int sscur[BSZ];

    const int tid = threadIdx.x;

    if (blockIdx.x < nbuck) {
        // ---------------- sortloc ----------------
        const int b    = blockIdx.x;
        const int base = b * CAP;
        const int cnt  = min(bcursor[b], CAP);

        scnt[tid] = 0;
        sscur[tid] = 0;
        __syncthreads();

        for (int i = tid; i < cnt; i += 256) {
            int p = tmp[base + i];
            sedge[i] = p;
            atomicAdd(&scnt[p & (BSZ - 1)], 1);
        }
        __syncthreads();

        int v = scnt[tid];
        spref[tid] = v;
        __syncthreads();
        for (int off = 1; off < 256; off <<= 1) {
            int t2 = (tid >= off) ? spref[tid - off] : 0;
            __syncthreads();
            spref[tid] += t2;
            __syncthreads();
        }
        int excl = spref[tid] - v;

        const int node = (b << BSHIFT) + tid;
        if (node < N) {
            rowptr[node] = base + excl;
            dis[node] = (v > 0) ? rsqrtf((float)v) : 0.f;
        }
        spref[tid] = excl;
        if (tid == 0) bend[b] = base + cnt;
        __syncthreads();

        for (int i = tid; i < cnt; i += 256) {
            int p = sedge[i];
            int c = p & (BSZ - 1);
            int pos = base + spref[c] + atomicAdd(&sscur[c], 1);
            tmp[pos] = p >> BSHIFT;
        }
    } else {
        // ---------------- MFMA linear (unscaled) ----------------
        const int lane6 = tid & 63;
        const int wv    = tid >> 6;
        const int tile    = (blockIdx.x - nbuck) * 4 + wv;
        const int rowbase = tile * 16;
        if (rowbase >= N) return;

        bf16x8 b[16];
#pragma unroll
        for (int f = 0; f < 16; ++f)
            b[f] = *reinterpret_cast<const bf16x8*>(&wtab[(f * 64 + lane6) * 4]);

        const int arow  = rowbase + (lane6 & 15);
        const int kbase = (lane6 >> 4) * 8;
        bf16x8 a[4];
#pragma unroll
        for (int kt = 0; kt < 4; ++kt) {
            const float4* p = reinterpret_cast<const float4*>(
                &x[(size_t)arow * IN_DIM + kt * 32 + kbase]);
            float4 f0 = p[0], f1 = p[1];
            unsigned int q[4] = { pk_bf2(f0.x, f0.y), pk_bf2(f0.z, f0.w),
                                  pk_bf2(f1.x, f1.y), pk_bf2(f1.z, f1.w) };
            a[kt] = *reinterpret_cast<bf16x8*>(q);
        }

        f32x4 acc[4] = {{0,0,0,0},{0,0,0,0},{0,0,0,0},{0,0,0,0}};
#pragma unroll
        for (int ct = 0; ct < 4; ++ct)
#pragma unroll
            for (int kt = 0; kt < 4; ++kt)
                acc[ct] = __builtin_amdgcn_mfma_f32_16x16x32_bf16(
                    a[kt], b[ct * 4 + kt], acc[ct], 0, 0, 0);

        const int rbase = rowbase + (lane6 >> 4) * 4;
#pragma unroll
        for (int ct = 0; ct < 4; ++ct) {
#pragma unroll
            for (int r = 0; r < 4; ++r) {
                float v  = acc[ct][r];
                float vn = __shfl_down(v, 1, 64);
                if ((lane6 & 1) == 0) {
                    int cpair = ct * 8 + ((lane6 & 15) >> 1);
                    hsb[(size_t)(rbase + r) * (OUT_DIM / 2) + cpair] = pk_bf2(v, vn);
                }
            }
        }
    }
}

// ---------------------------------------------------------------------------
// Aggregate + bias + PReLU, quarter-wave layout: each 16-lane quarter
// processes its own edge (16 lanes x uint2 = 128B row). 4 edges in flight
// per instruction slot; 4-deep unroll. Quarters combined via shfl_xor(16,32).
// ---------------------------------------------------------------------------
__global__ __launch_bounds__(256) void agg_kernel(
        const int* __restrict__ rowptr, const int* __restrict__ src,
        const int* __restrict__ bend,
        const uint2* __restrict__ hsb2, const float* __restrict__ dis,
        const float* __restrict__ b, const float* __restrict__ prelu_a,
        float* __restrict__ out, int N) {
    const int lane = threadIdx.x & 63;
    const int q    = lane >> 4;        // quarter 0..3
    const int s    = lane & 15;        // sublane within quarter
    const int node = (blockIdx.x * blockDim.x + threadIdx.x) >> 6;
    if (node >= N) return;

    const int beg = rowptr[node];
    const int nb1 = node + 1;
    const int end = ((nb1 & (BSZ - 1)) != 0 && nb1 < N) ? rowptr[nb1]
                                                        : bend[node >> BSHIFT];

    float a00 = 0.f, a01 = 0.f, a10 = 0.f, a11 = 0.f;
    int p = beg + q;

    // 4 slots x 4 quarters = 16 edges per iteration; 4 gathers in flight/lane
    for (; p + 12 < end; p += 16) {
        int r0 = src[p], r1 = src[p + 4], r2 = src[p + 8], r3 = src[p + 12];
        float s0 = dis[r0], s1 = dis[r1], s2 = dis[r2], s3 = dis[r3];
        uint2 v0 = hsb2[r0 * 16 + s];
        uint2 v1 = hsb2[r1 * 16 + s];
        uint2 v2 = hsb2[r2 * 16 + s];
        uint2 v3 = hsb2[r3 * 16 + s];
        a00 = fmaf(bf_lo(v0.x), s0, a00); a01 = fmaf(bf_hi(v0.x), s0, a01);
        a10 = fmaf(bf_lo(v0.y), s0, a10); a11 = fmaf(bf_hi(v0.y), s0, a11);
        a00 = fmaf(bf_lo(v1.x), s1, a00); a01 = fmaf(bf_hi(v1.x), s1, a01);
        a10 = fmaf(bf_lo(v1.y), s1, a10); a11 = fmaf(bf_hi(v1.y), s1, a11);
        a00 = fmaf(bf_lo(v2.x), s2, a00); a01 = fmaf(bf_hi(v2.x), s2, a01);
        a10 = fmaf(bf_lo(v2.y), s2, a10); a11 = fmaf(bf_hi(v2.y), s2, a11);
        a00 = fmaf(bf_lo(v3.x), s3, a00); a01 = fmaf(bf_hi(v3.x), s3, a01);
        a10 = fmaf(bf_lo(v3.y), s3, a10); a11 = fmaf(bf_hi(v3.y), s3, a11);
    }
    // 2 slots (8 edges)
    for (; p + 4 < end; p += 8) {
        int r0 = src[p], r1 = src[p + 4];
        float s0 = dis[r0], s1 = dis[r1];
        uint2 v0 = hsb2[r0 * 16 + s];
        uint2 v1 = hsb2[r1 * 16 + s];
        a00 = fmaf(bf_lo(v0.x), s0, a00); a01 = fmaf(bf_hi(v0.x), s0, a01);
        a10 = fmaf(bf_lo(v0.y), s0, a10); a11 = fmaf(bf_hi(v0.y), s0, a11);
        a00 = fmaf(bf_lo(v1.x), s1, a00); a01 = fmaf(bf_hi(v1.x), s1, a01);
        a10 = fmaf(bf_lo(v1.y), s1, a10); a11 = fmaf(bf_hi(v1.y), s1, a11);
    }
    // singles
    for (; p < end; p += 4) {
        int r = src[p];
        float sc = dis[r];
        uint2 v = hsb2[r * 16 + s];
        a00 = fmaf(bf_lo(v.x), sc, a00); a01 = fmaf(bf_hi(v.x), sc, a01);
        a10 = fmaf(bf_lo(v.y), sc, a10); a11 = fmaf(bf_hi(v.y), sc, a11);
    }

    // combine the 4 quarters
    a00 += __shfl_xor(a00, 16, 64); a00 += __shfl_xor(a00, 32, 64);
    a01 += __shfl_xor(a01, 16, 64); a01 += __shfl_xor(a01, 32, 64);
    a10 += __shfl_xor(a10, 16, 64); a10 += __shfl_xor(a10, 32, 64);
    a11 += __shfl_xor(a11, 16, 64); a11 += __shfl_xor(a11, 32, 64);

    if (q == 0) {
        const float dn = dis[node];
        const float pa = prelu_a[0];
        const int c0 = s * 4;
        float o0 = a00 * dn + b[c0];
        float o1 = a01 * dn + b[c0 + 1];
        float o2 = a10 * dn + b[c0 + 2];
        float o3 = a11 * dn + b[c0 + 3];
        o0 = (o0 >= 0.f) ? o0 : pa * o0;
        o1 = (o1 >= 0.f) ? o1 : pa * o1;
        o2 = (o2 >= 0.f) ? o2 : pa * o2;
        o3 = (o3 >= 0.f) ? o3 : pa * o3;
        *reinterpret_cast<float4*>(&out[(size_t)node * OUT_DIM + c0]) =
            make_float4(o0, o1, o2, o3);
    }
}

extern "C" void kernel_launch(void* const* d_in, const int* in_sizes, int n_in,
                              void* d_out, int out_size, void* d_ws, size_t ws_size,
                              hipStream_t stream) {
    const float* x    = (const float*)d_in[0];
    const int*   eidx = (const int*)d_in[1];
    const float* W    = (const float*)d_in[2];
    const float* b    = (const float*)d_in[3];
    const float* pa   = (const float*)d_in[4];
    float* out = (float*)d_out;

    const int N = in_sizes[0] / IN_DIM;        // 100000
    const int E = in_sizes[1] / 2;             // 1600000
    const int nbuck  = (N + BSZ - 1) >> BSHIFT;   // 391
    const int nchunk = (E + EPB - 1) / EPB;       // 391
    const int ntiles = (N + 15) / 16;             // 6250
    const int nblk_lin = (ntiles + 3) / 4;        // 1563

    // fixed bucket capacity: mean + 8 sigma, rounded to 256, capped by LDS
    int avg = E / nbuck;
    int CAP = ((avg + 8 * (int)sqrt((double)avg) + 255) / 256) * 256;
    if (CAP > CAPMAX) CAP = CAPMAX;

    // workspace layout (4-byte elements):
    unsigned int* hsb = (unsigned int*)d_ws;                  // N*32 (bf16x2)
    int*   bcursor = (int*)(hsb + (size_t)N * (OUT_DIM / 2)); // NBUCK_MAX
    int*   bend    = bcursor + NBUCK_MAX;                     // NBUCK_MAX
    int*   rowptr  = bend + NBUCK_MAX;                        // N
    float* dis     = (float*)(rowptr + N);                    // N
    int*   tmp     = (int*)(dis + N);                         // nbuck*CAP
    unsigned int* wtab = (unsigned int*)(tmp + (size_t)nbuck * CAP); // 4096

    // 1) zero bcursor + pack W frag table
    prep0_kernel<<<1, 256, 0, stream>>>(W, wtab, bcursor);

    // 2) bucket scatter (single global pass, register-staged)
    bucket_kernel<<<nchunk, 256, 0, stream>>>(eidx, bcursor, tmp, E, nbuck, CAP);

    // 3) fused: sortloc (count+scan+place, emits rowptr/dis/bend) || MFMA linear
    fusedB_kernel<<<nbuck + nblk_lin, 256, 0, stream>>>(
        tmp, bcursor, rowptr, dis, bend, x, wtab, hsb, N, CAP, nbuck);

    // 4) aggregate (quarter-wave uint2) + bias + PReLU
    agg_kernel<<<(N * 64 + 255) / 256, 256, 0, stream>>>(
        rowptr, tmp, bend, (const uint2*)hsb, dis, b, pa, out, N);
}

// Round 18
// 97.842 us; speedup vs baseline: 1.1680x; 1.0307x over previous
//
#include <hip/hip_runtime.h>
#include <hip/hip_bf16.h>
#include <math.h>

#define IN_DIM     128
#define OUT_DIM    64
#define BSHIFT     8                  // 256 nodes per bucket
#define BSZ        256
#define NBUCK_MAX  512                // covers N <= 131072
#define EPB        4096               // edges per block in bucket pass
#define EPT        16                 // edges per thread (EPB/256)
#define CAPMAX     5120               // LDS staging limit (20 KB)

typedef __attribute__((ext_vector_type(4))) float  f32x4;
typedef __attribute__((ext_vector_type(8))) short  bf16x8;

// bf16 helpers
__device__ __forceinline__ unsigned int pk_bf2(float lo, float hi) {
    __hip_bfloat162 h = __float22bfloat162_rn(make_float2(lo, hi));
    unsigned int u;
    __builtin_memcpy(&u, &h, 4);
    return u;
}
__device__ __forceinline__ float bf_lo(unsigned int v) { return __uint_as_float(v << 16); }
__device__ __forceinline__ float bf_hi(unsigned int v) { return __uint_as_float(v & 0xFFFF0000u); }

// ---------------------------------------------------------------------------
// Bucket scatter (single global pass, register-staged) + wtab pack.
//   blocks [0, nchunk): scatter packed (r<<8 | c&255) into tmp[b*CAP ...]
//   block nchunk:       pack W into MFMA B-frag order (bf16, 16 KB)
// bcursor must be pre-zeroed (hipMemsetAsync).
// ---------------------------------------------------------------------------
__global__ __launch_bounds__(256) void bucket_kernel(
        const int* __restrict__ eidx, const float* __restrict__ W,
        unsigned int* __restrict__ wtab, int* __restrict__ bcursor,
        int* __restrict__ tmp, int E, int nbuck, int CAP, int nchunk) {
    __shared__ int hcnt[NBUCK_MAX];
    __shared__ int hbase[NBUCK_MAX];
    const int tid = threadIdx.x;

    if (blockIdx.x == nchunk) {
        // ---------------- wtab pack (one block) ----------------
#pragma unroll
        for (int ii = 0; ii < 4; ++ii) {
            int fl = ii * 256 + tid, f = fl >> 6, lane = fl & 63;
            int ct = f >> 2, kt = f & 3;
            int n  = ct * 16 + (lane & 15);
            int kb = kt * 32 + (lane >> 4) * 8;
            unsigned int q[4];
#pragma unroll
            for (int e = 0; e < 4; ++e)
                q[e] = pk_bf2(W[(kb + 2 * e) * OUT_DIM + n],
                              W[(kb + 2 * e + 1) * OUT_DIM + n]);
            *reinterpret_cast<uint4*>(&wtab[fl * 4]) = *reinterpret_cast<uint4*>(q);
        }
        return;
    }

    // ---------------- bucket scatter ----------------
    for (int i = tid; i < nbuck; i += 256) hcnt[i] = 0;
    __syncthreads();

    const int base = blockIdx.x * EPB;
    const int* col = eidx + E;

    int er[EPT], ec[EPT];
#pragma unroll
    for (int j = 0; j < EPT; ++j) {
        int e = base + j * 256 + tid;
        if (e < E) {
            er[j] = eidx[e];
            ec[j] = col[e];
            atomicAdd(&hcnt[ec[j] >> BSHIFT], 1);
        } else {
            ec[j] = -1;
        }
    }
    __syncthreads();

    for (int i = tid; i < nbuck; i += 256) {
        int n = hcnt[i];
        hbase[i] = n ? (i * CAP + atomicAdd(&bcursor[i], n)) : 0;
        hcnt[i] = 0;                        // reuse as local cursor
    }
    __syncthreads();

#pragma unroll
    for (int j = 0; j < EPT; ++j) {
        if (ec[j] >= 0) {
            int bb = ec[j] >> BSHIFT;
            int ofs = atomicAdd(&hcnt[bb], 1);
            int pos = hbase[bb] + ofs;
            if (pos < (bb + 1) * CAP)       // overflow guard (8-sigma margin)
                tmp[pos] = (er[j] << BSHIFT) | (ec[j] & (BSZ - 1));
        }
    }
}

// ---------------------------------------------------------------------------
// fusedB (spatial partition, block-uniform branch):
//   blocks [0, nbuck):          sortloc = count + scan + in-place CSR
//                               placement; emits rowptr + dis + bend
//   blocks [nbuck, +nblk_lin):  MFMA linear, hsb = bf16(x @ W)  [UNscaled]
// ---------------------------------------------------------------------------
__global__ __launch_bounds__(256) void fusedB_kernel(
        int* __restrict__ tmp, const int* __restrict__ bcursor,
        int* __restrict__ rowptr, float* __restrict__ dis,
        int* __restrict__ bend,
        const float* __restrict__ x, const unsigned int* __restrict__ wtab,
        unsigned int* __restrict__ hsb, int N, int CAP, int nbuck) {
    __shared__ int sedge[CAPMAX];          // 20 KB
    __shared__ int scnt[BSZ];
    __shared__ int spref[BSZ];
    __shared__ int sscur[BSZ];

    const int tid = threadIdx.x;

    if (blockIdx.x < nbuck) {
        // ---------------- sortloc ----------------
        const int b    = blockIdx.x;
        const int base = b * CAP;
        const int cnt  = min(bcursor[b], CAP);

        scnt[tid] = 0;
        sscur[tid] = 0;
        __syncthreads();

        for (int i = tid; i < cnt; i += 256) {
            int p = tmp[base + i];
            sedge[i] = p;
            atomicAdd(&scnt[p & (BSZ - 1)], 1);
        }
        __syncthreads();

        int v = scnt[tid];
        spref[tid] = v;
        __syncthreads();
        for (int off = 1; off < 256; off <<= 1) {
            int t2 = (tid >= off) ? spref[tid - off] : 0;
            __syncthreads();
            spref[tid] += t2;
            __syncthreads();
        }
        int excl = spref[tid] - v;

        const int node = (b << BSHIFT) + tid;
        if (node < N) {
            rowptr[node] = base + excl;
            dis[node] = (v > 0) ? rsqrtf((float)v) : 0.f;
        }
        spref[tid] = excl;
        if (tid == 0) bend[b] = base + cnt;
        __syncthreads();

        for (int i = tid; i < cnt; i += 256) {
            int p = sedge[i];
            int c = p & (BSZ - 1);
            int pos = base + spref[c] + atomicAdd(&sscur[c], 1);
            tmp[pos] = p >> BSHIFT;
        }
    } else {
        // ---------------- MFMA linear (unscaled) ----------------
        const int lane6 = tid & 63;
        const int wv    = tid >> 6;
        const int tile    = (blockIdx.x - nbuck) * 4 + wv;
        const int rowbase = tile * 16;
        if (rowbase >= N) return;

        bf16x8 b[16];
#pragma unroll
        for (int f = 0; f < 16; ++f)
            b[f] = *reinterpret_cast<const bf16x8*>(&wtab[(f * 64 + lane6) * 4]);

        const int arow  = rowbase + (lane6 & 15);
        const int kbase = (lane6 >> 4) * 8;
        bf16x8 a[4];
#pragma unroll
        for (int kt = 0; kt < 4; ++kt) {
            const float4* p = reinterpret_cast<const float4*>(
                &x[(size_t)arow * IN_DIM + kt * 32 + kbase]);
            float4 f0 = p[0], f1 = p[1];
            unsigned int q[4] = { pk_bf2(f0.x, f0.y), pk_bf2(f0.z, f0.w),
                                  pk_bf2(f1.x, f1.y), pk_bf2(f1.z, f1.w) };
            a[kt] = *reinterpret_cast<bf16x8*>(q);
        }

        f32x4 acc[4] = {{0,0,0,0},{0,0,0,0},{0,0,0,0},{0,0,0,0}};
#pragma unroll
        for (int ct = 0; ct < 4; ++ct)
#pragma unroll
            for (int kt = 0; kt < 4; ++kt)
                acc[ct] = __builtin_amdgcn_mfma_f32_16x16x32_bf16(
                    a[kt], b[ct * 4 + kt], acc[ct], 0, 0, 0);

        const int rbase = rowbase + (lane6 >> 4) * 4;
#pragma unroll
        for (int ct = 0; ct < 4; ++ct) {
#pragma unroll
            for (int r = 0; r < 4; ++r) {
                float v  = acc[ct][r];
                float vn = __shfl_down(v, 1, 64);
                if ((lane6 & 1) == 0) {
                    int cpair = ct * 8 + ((lane6 & 15) >> 1);
                    hsb[(size_t)(rbase + r) * (OUT_DIM / 2) + cpair] = pk_bf2(v, vn);
                }
            }
        }
    }
}

// ---------------------------------------------------------------------------
// Aggregate + bias + PReLU, eighth-wave layout: each 8-lane eighth processes
// its own edge (8 lanes x uint4 = 128B row). 8 edges per instruction slot,
// 2-deep unroll = 16 edges in flight/wave. Eighths combined via
// shfl_xor(8,16,32).
// ---------------------------------------------------------------------------
__global__ __launch_bounds__(256) void agg_kernel(
        const int* __restrict__ rowptr, const int* __restrict__ src,
        const int* __restrict__ bend,
        const uint4* __restrict__ hsb4, const float* __restrict__ dis,
        const float* __restrict__ b, const float* __restrict__ prelu_a,
        float* __restrict__ out, int N) {
    const int lane = threadIdx.x & 63;
    const int e8   = lane >> 3;        // eighth 0..7
    const int s    = lane & 7;         // sublane within eighth
    const int node = (blockIdx.x * blockDim.x + threadIdx.x) >> 6;
    if (node >= N) return;

    const int beg = rowptr[node];
    const int nb1 = node + 1;
    const int end = ((nb1 & (BSZ - 1)) != 0 && nb1 < N) ? rowptr[nb1]
                                                        : bend[node >> BSHIFT];

    float a0 = 0.f, a1 = 0.f, a2 = 0.f, a3 = 0.f;
    float a4 = 0.f, a5 = 0.f, a6 = 0.f, a7 = 0.f;
    int p = beg + e8;

    // 2 slots x 8 eighths = 16 edges per iteration, 2 gathers in flight/lane
    for (; p + 8 < end; p += 16) {
        int r0 = src[p], r1 = src[p + 8];
        float s0 = dis[r0], s1 = dis[r1];
        uint4 v0 = hsb4[r0 * 8 + s];
        uint4 v1 = hsb4[r1 * 8 + s];
        a0 = fmaf(bf_lo(v0.x), s0, a0); a1 = fmaf(bf_hi(v0.x), s0, a1);
        a2 = fmaf(bf_lo(v0.y), s0, a2); a3 = fmaf(bf_hi(v0.y), s0, a3);
        a4 = fmaf(bf_lo(v0.z), s0, a4); a5 = fmaf(bf_hi(v0.z), s0, a5);
        a6 = fmaf(bf_lo(v0.w), s0, a6); a7 = fmaf(bf_hi(v0.w), s0, a7);
        a0 = fmaf(bf_lo(v1.x), s1, a0); a1 = fmaf(bf_hi(v1.x), s1, a1);
        a2 = fmaf(bf_lo(v1.y), s1, a2); a3 = fmaf(bf_hi(v1.y), s1, a3);
        a4 = fmaf(bf_lo(v1.z), s1, a4); a5 = fmaf(bf_hi(v1.z), s1, a5);
        a6 = fmaf(bf_lo(v1.w), s1, a6); a7 = fmaf(bf_hi(v1.w), s1, a7);
    }
    // singles (one edge per eighth)
    for (; p < end; p += 8) {
        int r = src[p];
        float sc = dis[r];
        uint4 v = hsb4[r * 8 + s];
        a0 = fmaf(bf_lo(v.x), sc, a0); a1 = fmaf(bf_hi(v.x), sc, a1);
        a2 = fmaf(bf_lo(v.y), sc, a2); a3 = fmaf(bf_hi(v.y), sc, a3);
        a4 = fmaf(bf_lo(v.z), sc, a4); a5 = fmaf(bf_hi(v.z), sc, a5);
        a6 = fmaf(bf_lo(v.w), sc, a6); a7 = fmaf(bf_hi(v.w), sc, a7);
    }

    // combine the 8 eighths (lane bits 3,4,5)
    float acc[8] = { a0, a1, a2, a3, a4, a5, a6, a7 };
#pragma unroll
    for (int k = 0; k < 8; ++k) {
        acc[k] += __shfl_xor(acc[k], 8, 64);
        acc[k] += __shfl_xor(acc[k], 16, 64);
        acc[k] += __shfl_xor(acc[k], 32, 64);
    }

    if (e8 == 0) {
        const float dn = dis[node];
        const float pa = prelu_a[0];
        const int c0 = s * 8;
        float o[8];
#pragma unroll
        for (int k = 0; k < 8; ++k) {
            float v = acc[k] * dn + b[c0 + k];
            o[k] = (v >= 0.f) ? v : pa * v;
        }
        float4* po = reinterpret_cast<float4*>(&out[(size_t)node * OUT_DIM + c0]);
        po[0] = make_float4(o[0], o[1], o[2], o[3]);
        po[1] = make_float4(o[4], o[5], o[6], o[7]);
    }
}

extern "C" void kernel_launch(void* const* d_in, const int* in_sizes, int n_in,
                              void* d_out, int out_size, void* d_ws, size_t ws_size,
                              hipStream_t stream) {
    const float* x    = (const float*)d_in[0];
    const int*   eidx = (const int*)d_in[1];
    const float* W    = (const float*)d_in[2];
    const float* b    = (const float*)d_in[3];
    const float* pa   = (const float*)d_in[4];
    float* out = (float*)d_out;

    const int N = in_sizes[0] / IN_DIM;        // 100000
    const int E = in_sizes[1] / 2;             // 1600000
    const int nbuck  = (N + BSZ - 1) >> BSHIFT;   // 391
    const int nchunk = (E + EPB - 1) / EPB;       // 391
    const int ntiles = (N + 15) / 16;             // 6250
    const int nblk_lin = (ntiles + 3) / 4;        // 1563

    // fixed bucket capacity: mean + 8 sigma, rounded to 256, capped by LDS
    int avg = E / nbuck;
    int CAP = ((avg + 8 * (int)sqrt((double)avg) + 255) / 256) * 256;
    if (CAP > CAPMAX) CAP = CAPMAX;

    // workspace layout (4-byte elements):
    unsigned int* hsb = (unsigned int*)d_ws;                  // N*32 (bf16x2)
    int*   bcursor = (int*)(hsb + (size_t)N * (OUT_DIM / 2)); // NBUCK_MAX
    int*   bend    = bcursor + NBUCK_MAX;                     // NBUCK_MAX
    int*   rowptr  = bend + NBUCK_MAX;                        // N
    float* dis     = (float*)(rowptr + N);                    // N
    int*   tmp     = (int*)(dis + N);                         // nbuck*CAP
    unsigned int* wtab = (unsigned int*)(tmp + (size_t)nbuck * CAP); // 4096

    // 1) zero bcursor (graph-capturable memset node)
    hipMemsetAsync(bcursor, 0, NBUCK_MAX * sizeof(int), stream);

    // 2) bucket scatter (single global pass) + wtab pack (extra block)
    bucket_kernel<<<nchunk + 1, 256, 0, stream>>>(
        eidx, W, wtab, bcursor, tmp, E, nbuck, CAP, nchunk);

    // 3) fused: sortloc (count+scan+place, emits rowptr/dis/bend) || MFMA linear
    fusedB_kernel<<<nbuck + nblk_lin, 256, 0, stream>>>(
        tmp, bcursor, rowptr, dis, bend, x, wtab, hsb, N, CAP, nbuck);

    // 4) aggregate (eighth-wave uint4) + bias + PReLU
    agg_kernel<<<(N * 64 + 255) / 256, 256, 0, stream>>>(
        rowptr, tmp, bend, (const uint4*)hsb, dis, b, pa, out, N);
}